// Round 6
// baseline (315.372 us; speedup 1.0000x reference)
//
#include <hip/hip_runtime.h>
#include <stdint.h>

// ---------------------------------------------------------------------------
// AvgClicksPoolingInitializer  (B=8, I=16, C=256)
// Levels: L=0..3  w=128>>L, P=w*w, k=4<<L (scribble 512 / w)
// m[y][x] = 0.25*(S[r0][c0]+S[r0][c1]+S[r1][c0]+S[r1][c1]),
// r0 = k*y + k/2 - 1, c0 = k*x + k/2 - 1.   sel = (m > 0.5)  <=>  sum4 > 2.0
//
// History: cross-lane shuffles (R1), per-i serialized load chains (R2),
// device-scope atomics (R4), imbalanced L-major grid (R5) each cost 50-100us.
// Cooperative grid.sync() scales ~linearly with grid size and collapses BW
// (R6/R8: 512blk ~115us, 2048blk ~460us sync+spin) — kernel boundaries are
// cheap on MI355X, grid sync is catastrophic. ~219us of dur_us is the
// harness's fixed 512MiB workspace re-poison fill (outside kernel control).
// R10 (3 plain kernels, mask+ballot / pool / final) = 313us; kernels ~94us
// vs ~60-65us traffic floor.
// R11 (this round): final3 was 128 blocks (0.5 blk/CU) with a serialized
// 64-deep load+add chain per thread (latency-bound suspect). Restructured:
// 1024 blocks = (b,i,c-group-of-32); 256 thr = 32c x 8 sp-slices; chains
// cut 85 -> <=11, parallelism x8. mask_flat / pool_direct byte-identical
// (passed twice).
// ---------------------------------------------------------------------------

#define NI 16
#define NB 8
#define NC 256
#define PTOT 21760   // 16384+4096+1024+256

#define SPL0 64
#define SPL1 16
#define SPL2 4
#define SPL3 1
#define NSP  85      // 64+16+4+1
#define PLANE (NB * NI * NC)   // 32768 floats per split-plane

#define MASK_UNITS 2720       // 2048+512+128+32  (P/64 units per (L,b))
#define POOL_WAVES 10880      // 8192+2048+512+128

typedef __attribute__((ext_vector_type(8))) short bf16x8;
typedef __attribute__((ext_vector_type(4))) float f32x4;

__device__ __forceinline__ int level_off(int L) {
    return (L == 0) ? 0 : (L == 1) ? 16384 : (L == 2) ? 20480 : 21504;
}

__device__ __forceinline__ unsigned int ordered_bits(float v) {
    unsigned int u = __float_as_uint(v);
    return u ^ ((u >> 31) ? 0xFFFFFFFFu : 0x80000000u);
}

__device__ __forceinline__ unsigned short f2bf(float x) {   // RNE, finite inputs
    unsigned int u = __float_as_uint(x);
    u += 0x7FFFu + ((u >> 16) & 1u);
    return (unsigned short)(u >> 16);
}

// ---------------------------------------------------------------------------
// Kernel 1: mask + ballot counts. Flat 2720-block grid (no early-exit waste).
// Block = one 64-pixel unit of one (L,b); 4 waves = 4 instance groups; each
// thread handles 4 instances with ALL loads batched (one latency round-trip).
// cntpart[u0][i] = per-unit popcount for instance i (summed in final3).
// ---------------------------------------------------------------------------
__global__ __launch_bounds__(256) void mask_flat(
        const float* __restrict__ scr,          // (8,16,512,512)
        unsigned short* __restrict__ selm,      // (8, PTOT)
        unsigned int* __restrict__ cntpart) {   // (MASK_UNITS, 16)
    const int u0 = blockIdx.x;
    int u = u0, L, b, bx;
    if (u < 2048)                { L = 0; b = u >> 8; bx = u & 255; }
    else if ((u -= 2048) < 512)  { L = 1; b = u >> 6; bx = u & 63;  }
    else if ((u -= 512) < 128)   { L = 2; b = u >> 4; bx = u & 15;  }
    else { u -= 128;             L = 3; b = u >> 2; bx = u & 3;   }

    const int wl2 = 7 - L;
    const int w = 1 << wl2;
    const int k = 4 << L;
    const int tx = threadIdx.x & 63;
    const int g  = threadIdx.x >> 6;            // instance group 0..3
    const int p = bx * 64 + tx;
    const int y = p >> wl2, x = p & (w - 1);
    const int r0 = k * y + (k >> 1) - 1;
    const int c0 = k * x + (k >> 1) - 1;
    const int off = level_off(L);
    const float* Sg = scr + (size_t)(b * NI + g * 4) * 262144 + r0 * 512 + c0;

    float v[4];
    if (k == 4) {
        // c0 = 4x+1: aligned float4 at col 4x; need .y,.z
        float4 t0[4], t1[4];
#pragma unroll
        for (int j = 0; j < 4; ++j) {
            const float* Si = Sg + (size_t)j * 262144;
            t0[j] = *(const float4*)(Si - 1);
            t1[j] = *(const float4*)(Si - 1 + 512);
        }
#pragma unroll
        for (int j = 0; j < 4; ++j)
            v[j] = (t0[j].y + t0[j].z) + (t1[j].y + t1[j].z);
    } else {
        float a0[4], a1[4], a2[4], a3[4];
#pragma unroll
        for (int j = 0; j < 4; ++j) {
            const float* Si = Sg + (size_t)j * 262144;
            a0[j] = Si[0]; a1[j] = Si[1]; a2[j] = Si[512]; a3[j] = Si[513];
        }
#pragma unroll
        for (int j = 0; j < 4; ++j)
            v[j] = (a0[j] + a1[j]) + (a2[j] + a3[j]);
    }

    unsigned int nib = 0;
#pragma unroll
    for (int j = 0; j < 4; ++j)
        nib |= (v[j] > 2.0f) ? (1u << j) : 0u;

    // counts: free per-wave ballot (bit already computed), no atomics
#pragma unroll
    for (int j = 0; j < 4; ++j) {
        unsigned long long bm = __ballot(v[j] > 2.0f);
        if (tx == 0)
            cntpart[(size_t)u0 * 16 + g * 4 + j] = (unsigned int)__popcll(bm);
    }

    __shared__ unsigned int sh[4][64];
    sh[g][tx] = nib << (g * 4);
    __syncthreads();
    if (threadIdx.x < 64) {
        selm[(size_t)b * PTOT + off + bx * 64 + threadIdx.x] =
            (unsigned short)(sh[0][threadIdx.x] | sh[1][threadIdx.x] |
                             sh[2][threadIdx.x] | sh[3][threadIdx.x]);
    }
}

// ---------------------------------------------------------------------------
// Kernel 2: LDS-free MFMA pooling, flat balanced grid.
// One wave per (L, b, c-tile of 16, split); every wave does exactly 8
// contiguous K-steps of 32. All 24 loads batched up front.
//   A[m=lane&15][k=quad*8+j] = bit m of selmask[p0+quad*8+j]
//   B[k=quad*8+j][n=lane&15] = f[c0+n][p0+quad*8+j]
// Partials to per-(L,split) planes; no atomics, no memset.
// waves: L0 8*16*64=8192, L1 2048, L2 512, L3 128 -> 10880 = 2720 blocks
// ---------------------------------------------------------------------------
__global__ __launch_bounds__(256) void pool_direct(
        const float* __restrict__ f0, const float* __restrict__ f1,
        const float* __restrict__ f2, const float* __restrict__ f3,
        const unsigned short* __restrict__ selmask,
        float* __restrict__ swp) {              // NSP planes of (8,16,256)
    const int wid = blockIdx.x * 4 + (threadIdx.x >> 6);
    const int lane = threadIdx.x & 63;
    const int n = lane & 15, quad = lane >> 4;

    int L, b, ct, sp, lvlbase;
    {
        int u = wid;
        if (u < 8192)              { L = 0; sp = u & 63; ct = (u >> 6) & 15; b = u >> 10; lvlbase = 0;  }
        else if ((u -= 8192) < 2048) { L = 1; sp = u & 15; ct = (u >> 4) & 15; b = u >> 8;  lvlbase = 64; }
        else if ((u -= 2048) < 512)  { L = 2; sp = u & 3;  ct = (u >> 2) & 15; b = u >> 6;  lvlbase = 80; }
        else { u -= 512;             L = 3; sp = 0;      ct = u & 15;        b = u >> 4;  lvlbase = 84; }
    }

    const int P = 16384 >> (2 * L);
    const float* fL = (L == 0) ? f0 : (L == 1) ? f1 : (L == 2) ? f2 : f3;
    const float* frow = fL + (size_t)(b * NC + ct * 16 + n) * P + quad * 8;
    const unsigned short* selb = selmask + (size_t)b * PTOT + level_off(L) + quad * 8;
    const int p00 = sp * 8 * 32;                // contiguous 8 K-steps

    // ---- batch ALL loads (one latency round-trip per wave)
    float4 uf[16];
    uint4  um[8];
#pragma unroll
    for (int j = 0; j < 8; ++j) {
        const int p0 = p00 + j * 32;
        uf[2 * j]     = *(const float4*)(frow + p0);
        uf[2 * j + 1] = *(const float4*)(frow + p0 + 4);
        um[j]         = *(const uint4*)(selb + p0);
    }

    f32x4 acc = {0.f, 0.f, 0.f, 0.f};
#pragma unroll
    for (int j = 0; j < 8; ++j) {
        bf16x8 bv;
        bv[0] = (short)f2bf(uf[2*j].x);   bv[1] = (short)f2bf(uf[2*j].y);
        bv[2] = (short)f2bf(uf[2*j].z);   bv[3] = (short)f2bf(uf[2*j].w);
        bv[4] = (short)f2bf(uf[2*j+1].x); bv[5] = (short)f2bf(uf[2*j+1].y);
        bv[6] = (short)f2bf(uf[2*j+1].z); bv[7] = (short)f2bf(uf[2*j+1].w);

        bf16x8 av;
        const unsigned int uu[4] = {um[j].x, um[j].y, um[j].z, um[j].w};
#pragma unroll
        for (int t = 0; t < 4; ++t) {
            const unsigned int lo = uu[t] & 0xFFFFu, hi = uu[t] >> 16;
            av[2 * t]     = ((lo >> n) & 1u) ? (short)0x3F80 : (short)0;
            av[2 * t + 1] = ((hi >> n) & 1u) ? (short)0x3F80 : (short)0;
        }
        acc = __builtin_amdgcn_mfma_f32_16x16x32_bf16(av, bv, acc, 0, 0, 0);
    }

    // ---- epilogue: D[m=i][n=c]: col=lane&15, row=quad*4+r
    float* plane = swp + (size_t)(lvlbase + sp) * PLANE;
    const int ccol = ct * 16 + n;
#pragma unroll
    for (int r = 0; r < 4; ++r) {
        const int i = quad * 4 + r;
        plane[(size_t)(b * NI + i) * NC + ccol] = acc[r];
    }
}

// ---------------------------------------------------------------------------
// Kernel 3 (restructured R11): 1024 blocks = (b,i) x 8 c-groups of 32.
// 256 threads = 32 c x 8 sp-slices. Each thread sums sp = slice::8 of the
// split planes (chain <=8 for L0, <=2 for L1, <=1 for L2/L3; four level
// accumulators independent -> loads pipeline). /cnt distributes over the
// slice partials. Counts + rare argmax duplicated per c-group (L2-resident,
// cheap; argmax predicate stays block-uniform).
// ---------------------------------------------------------------------------
__global__ __launch_bounds__(256) void final3(
        const float* __restrict__ f0, const float* __restrict__ f1,
        const float* __restrict__ f2, const float* __restrict__ f3,
        const float* __restrict__ scr,
        const float* __restrict__ swp,
        const unsigned int* __restrict__ cntpart,
        float* __restrict__ out) {
    const int bi = blockIdx.x >> 3;             // 0..127 = b*16+i
    const int cg = blockIdx.x & 7;              // c-group of 32
    const int b = bi >> 4, i = bi & 15;
    const int t = threadIdx.x;
    const int cl = t & 31;                      // c within group
    const int slice = t >> 5;                   // sp-slice 0..7
    const int c = cg * 32 + cl;
    const int nbxA[4]  = {256, 64, 16, 4};
    const int baseA[4] = {0, 2048, 2560, 2688};

    __shared__ unsigned long long red[256];
    __shared__ unsigned int cnt4[4], amax4[4];
    __shared__ float sacc[8][32];

    // sum ballot partials; pack 4 x 16-bit counts (<=16384 each) in 1 ull
    unsigned long long packed = 0ull;
#pragma unroll
    for (int L = 0; L < 4; ++L) {
        unsigned int s = 0;
        for (int bx = t; bx < nbxA[L]; bx += 256)
            s += cntpart[(size_t)(baseA[L] + b * nbxA[L] + bx) * 16 + i];
        packed |= (unsigned long long)s << (16 * L);
    }
    red[t] = packed;
    __syncthreads();
#pragma unroll
    for (int s = 128; s > 0; s >>= 1) {
        if (t < s) red[t] += red[t + s];
        __syncthreads();
    }
    if (t < 4) cnt4[t] = (unsigned int)((red[0] >> (16 * t)) & 0xFFFFull);
    __syncthreads();

    // rare path: argmax of resized mask, first-index tie-break
#pragma unroll
    for (int L = 0; L < 4; ++L) {
        if (cnt4[L] == 0) {                     // block-uniform predicate
            const int wl2 = 7 - L;
            const int w = 1 << wl2;
            const int P = 1 << (2 * wl2);
            const int k = 4 << L;
            const float* Si = scr + (size_t)(b * NI + i) * 262144;
            unsigned long long key = 0ull;
            for (int p = t; p < P; p += 256) {
                const int y = p >> wl2, x = p & (w - 1);
                const int r0 = k * y + (k >> 1) - 1;
                const int c0 = k * x + (k >> 1) - 1;
                const float* S = Si + r0 * 512 + c0;
                const float vv = (S[0] + S[1]) + (S[512] + S[513]);
                const unsigned long long kk =
                    ((unsigned long long)ordered_bits(vv) << 32)
                  | (unsigned long long)(0xFFFFFFFFu - (unsigned int)p);
                if (kk > key) key = kk;
            }
            __syncthreads();                    // red reuse guard
            red[t] = key;
            __syncthreads();
            for (int s = 128; s > 0; s >>= 1) {
                if (t < s && red[t + s] > red[t]) red[t] = red[t + s];
                __syncthreads();
            }
            if (t == 0)
                amax4[L] = 0xFFFFFFFFu - (unsigned int)(red[0] & 0xFFFFFFFFull);
            __syncthreads();
        }
    }

    // slice-parallel split-plane sums (independent per-level accumulators)
    const int splA[4]  = {SPL0, SPL1, SPL2, SPL3};
    const int lvlbA[4] = {0, 64, 80, 84};
    const size_t basebi = (size_t)bi * NC + c;
    float acc = 0.0f;
#pragma unroll
    for (int L = 0; L < 4; ++L) {
        const unsigned int cc = cnt4[L];
        if (cc > 0) {
            float s = 0.0f;
            for (int sp = slice; sp < splA[L]; sp += 8)
                s += swp[(size_t)(lvlbA[L] + sp) * PLANE + basebi];
            acc += s / (float)cc;
        } else if (slice == 0) {
            const float* fL = (L == 0) ? f0 : (L == 1) ? f1 : (L == 2) ? f2 : f3;
            const int P = 16384 >> (2 * L);
            acc += fL[(size_t)(b * NC + c) * P + amax4[L]];
        }
    }
    sacc[slice][cl] = acc;
    __syncthreads();
    if (slice == 0) {
        float s = ((sacc[0][cl] + sacc[1][cl]) + (sacc[2][cl] + sacc[3][cl]))
                + ((sacc[4][cl] + sacc[5][cl]) + (sacc[6][cl] + sacc[7][cl]));
        out[(size_t)bi * NC + c] = s * 0.25f;
    }
}

extern "C" void kernel_launch(void* const* d_in, const int* in_sizes, int n_in,
                              void* d_out, int out_size, void* d_ws, size_t ws_size,
                              hipStream_t stream) {
    (void)in_sizes; (void)n_in; (void)out_size; (void)ws_size;
    const float* f0  = (const float*)d_in[0];   // (8,256,128,128)
    const float* f1  = (const float*)d_in[1];   // (8,256,64,64)
    const float* f2  = (const float*)d_in[2];   // (8,256,32,32)
    const float* f3  = (const float*)d_in[3];   // (8,256,16,16)
    const float* scr = (const float*)d_in[4];   // (8,16,512,512)
    float* outp = (float*)d_out;                // (8,16,256) fp32

    char* ws = (char*)d_ws;
    const size_t SWP_SZ = (size_t)NSP * PLANE * 4;            // 11,141,120
    const size_t SEL_SZ = (size_t)NB * PTOT * 2;              //    348,160
    // layout: [swp | selm | cntpart]
    float*          swp  = (float*)ws;
    unsigned short* selm = (unsigned short*)(ws + SWP_SZ);
    unsigned int*   cntp = (unsigned int*)(ws + SWP_SZ + SEL_SZ);

    mask_flat<<<MASK_UNITS, 256, 0, stream>>>(scr, selm, cntp);
    pool_direct<<<MASK_UNITS, 256, 0, stream>>>(f0, f1, f2, f3, selm, swp);
    final3<<<NB * NI * 8, 256, 0, stream>>>(f0, f1, f2, f3, scr, swp, cntp, outp);
}